// Round 6
// baseline (6446.586 us; speedup 1.0000x reference)
//
#include <hip/hip_runtime.h>

// HighwayLayerDiscrete: 256-step recurrent highway net, batch 64, units 1024.
// Step t: h1=lrelu(y@w_y+xp[t]); h2=lrelu(h1@Wh0+b0); h3=lrelu(h2@Wh1+b1);
// y += h3@w_out + b_out; out[:,t,:]=y.   u-recurrence (R12): u += h3@W2 + c2,
// h1' = lrelu(u + xp[t+1]), W2 = w_out@w_y (per-thread frags in w2reg).
//
// R13 = R12 (4.83 ms) + SPLIT-BATCH 2-CHAIN PIPELINE: rows 0-31 = chain A,
// rows 32-63 = chain B — independent recurrences. Each WG alternates
// A-half/B-half per superphase S (768 total); stage-load RT and post->poll
// latency of one chain hide under the other chain's compute+finalize.
// R12 post-mortem: its "off-chain" y-block ran in lockstep across WGs =
// pure serial add; here the j2 y-matmul is FOLDED into the j2 compute
// (TILE4D reads a once -> acc(W2) + accY(w_out)), one red2 round of
// 128 u + 128 y partials, y-lanes = tid 128..255, out-store after post.
// Both chains share wreg (same j each superphase). red2 time-shared
// (barrier-separated). Flags: proven sc1 protocol x2 (A:0..255, B:256..511
// = exactly the 512-uint footprint). Per-output math identical to R12.
// Carried invariants: 256 coop blocks x 512 thr (R4); no cross-WG split-K
// (R2/R3); no cache fences (R1); sc1 device-scope exchange only (R10);
// release = waitcnt0+barrier+flag; acquire = wave0 32-lane poll + barrier
// + clobber; per-producer flags (R8); K-retile, unique W frags, de-aliased
// red2 (R9); LDS skew injective (R5); W2 prologue (R12).

constexpr int B = 64, T = 256, U = 1024, E = 512;
constexpr int BU = B * U;     // 65536
constexpr int APITCH = 1156;  // A-row pitch (1024 + 36-skew; ==4 mod 8)
constexpr int RPITCH = 264;   // red2 slice pitch (256 + 8)
constexpr int WOPITCH = 9;    // prologue w_out_s pitch

#define LRELU(v) ((v) > 0.f ? (v) : 0.2f * (v))

using f4 = float __attribute__((ext_vector_type(4)));

__device__ __forceinline__ void llc_store(float* p, float v) {
  __hip_atomic_store(p, v, __ATOMIC_RELAXED, __HIP_MEMORY_SCOPE_AGENT);
}
__device__ __forceinline__ unsigned llc_flag(const unsigned* p) {
  return __hip_atomic_load(p, __ATOMIC_RELAXED, __HIP_MEMORY_SCOPE_AGENT);
}
__device__ __forceinline__ void llc_post(unsigned* p, unsigned v) {
  __hip_atomic_store(p, v, __ATOMIC_RELAXED, __HIP_MEMORY_SCOPE_AGENT);
}

// 4-row x 4-col x K=16 tile: single W bank
#define TILE4(ACC, WB, AS)                                                \
  do {                                                                    \
    _Pragma("unroll") for (int q = 0; q < 4; ++q) {                       \
      const f4 w0 = WB[4 * q], w1 = WB[4 * q + 1];                        \
      const f4 w2v = WB[4 * q + 2], w3 = WB[4 * q + 3];                   \
      const int ab = abase_k + 4 * q;                                     \
      _Pragma("unroll") for (int r = 0; r < 4; ++r) {                     \
        f4 a = *(const f4*)&AS[r * APITCH + ab];                          \
        ACC[r] += a.x * w0 + a.y * w1 + a.z * w2v + a.w * w3;             \
      }                                                                   \
    }                                                                     \
  } while (0)
// dual: read a once, accumulate vs two W banks (j2: W2 -> ACC, w_out -> ACCY)
#define TILE4D(ACC, ACCY, WBM, WBY, AS)                                   \
  do {                                                                    \
    _Pragma("unroll") for (int q = 0; q < 4; ++q) {                       \
      const f4 m0 = WBM[4 * q], m1 = WBM[4 * q + 1];                      \
      const f4 m2 = WBM[4 * q + 2], m3 = WBM[4 * q + 3];                  \
      const f4 y0 = WBY[4 * q], y1 = WBY[4 * q + 1];                      \
      const f4 y2 = WBY[4 * q + 2], y3 = WBY[4 * q + 3];                  \
      const int ab = abase_k + 4 * q;                                     \
      _Pragma("unroll") for (int r = 0; r < 4; ++r) {                     \
        f4 a = *(const f4*)&AS[r * APITCH + ab];                          \
        ACC[r] += a.x * m0 + a.y * m1 + a.z * m2 + a.w * m3;              \
        ACCY[r] += a.x * y0 + a.y * y1 + a.z * y2 + a.w * y3;             \
      }                                                                   \
    }                                                                     \
  } while (0)
#define RED64(SUM)                                                        \
  float SUM;                                                              \
  do {                                                                    \
    float s0 = 0.f, s1 = 0.f, s2 = 0.f, s3 = 0.f;                         \
    _Pragma("unroll") for (int z = 0; z < 64; z += 4) {                   \
      s0 += red2[(z + 0) * RPITCH + tid];                                 \
      s1 += red2[(z + 1) * RPITCH + tid];                                 \
      s2 += red2[(z + 2) * RPITCH + tid];                                 \
      s3 += red2[(z + 3) * RPITCH + tid];                                 \
    }                                                                     \
    SUM = (s0 + s1) + (s2 + s3);                                          \
  } while (0)

// ---------------- init: zero flags (A + B arrays) ----------------
__global__ void k_init(unsigned* __restrict__ flags) {
  int tid = blockIdx.x * 256 + threadIdx.x;
  if (tid < 512) flags[tid] = 0u;
}

// ------- xproj[t*64+n][u] = emb[x[n][t]] @ w_x + b_in (R2/R3-proven) -------
__global__ __launch_bounds__(256) void k_xproj(
    const int* __restrict__ x, const float* __restrict__ emb,
    const float* __restrict__ w_x, const float* __restrict__ b_in,
    float* __restrict__ xp) {
  __shared__ float a_s[64][36];
  __shared__ float w_s[32][64];
  __shared__ int idxs[64];
  const int tid = threadIdx.x;
  const int m0 = blockIdx.x * 64;
  const int c0 = blockIdx.y * 64;
  if (tid < 64) {
    int m = m0 + tid;
    idxs[tid] = x[(m & 63) * T + (m >> 6)];  // x[n][t], row m = t*64+n
  }
  __syncthreads();
  const int rq = tid >> 4, cq = tid & 15;
  float acc[4][4] = {};
  for (int k0 = 0; k0 < E; k0 += 32) {
#pragma unroll
    for (int rep = 0; rep < 8; ++rep) {
      int e = rep * 256 + tid;
      int r = e >> 5, k = e & 31;
      a_s[r][k] = emb[(size_t)idxs[r] * E + k0 + k];
    }
#pragma unroll
    for (int rep = 0; rep < 2; ++rep) {
      int e = rep * 256 + tid;
      int kr = e >> 4, q = e & 15;
      *(float4*)&w_s[kr][4 * q] =
          *(const float4*)(w_x + (size_t)(k0 + kr) * U + c0 + 4 * q);
    }
    __syncthreads();
#pragma unroll
    for (int kc = 0; kc < 32; kc += 4) {
      float4 a4[4], w4[4];
#pragma unroll
      for (int i = 0; i < 4; ++i) a4[i] = *(const float4*)&a_s[4 * rq + i][kc];
#pragma unroll
      for (int kk = 0; kk < 4; ++kk)
        w4[kk] = *(const float4*)&w_s[kc + kk][4 * cq];
#pragma unroll
      for (int i = 0; i < 4; ++i) {
        const float av[4] = {a4[i].x, a4[i].y, a4[i].z, a4[i].w};
#pragma unroll
        for (int kk = 0; kk < 4; ++kk) {
          acc[i][0] += av[kk] * w4[kk].x;
          acc[i][1] += av[kk] * w4[kk].y;
          acc[i][2] += av[kk] * w4[kk].z;
          acc[i][3] += av[kk] * w4[kk].w;
        }
      }
    }
    __syncthreads();
  }
  const float4 bb = *(const float4*)(b_in + c0 + 4 * cq);
  const float bv[4] = {bb.x, bb.y, bb.z, bb.w};
#pragma unroll
  for (int i = 0; i < 4; ++i) {
    float4 o;
    o.x = acc[i][0] + bv[0];
    o.y = acc[i][1] + bv[1];
    o.z = acc[i][2] + bv[2];
    o.w = acc[i][3] + bv[3];
    *(float4*)(xp + (size_t)(m0 + 4 * rq + i) * U + c0 + 4 * cq) = o;
  }
}

// ---------------- sequential 2-chain pipeline ----------------
__global__ __launch_bounds__(512, 2) void k_seq(
    const float* __restrict__ xp, const float* __restrict__ w_y,
    const float* __restrict__ w_h, const float* __restrict__ b_h,
    const float* __restrict__ w_out, const float* __restrict__ b_out,
    const float* __restrict__ h0, float* __restrict__ out,
    float* __restrict__ slots, unsigned* __restrict__ flags) {
  __shared__ float a_sA[4 * APITCH];   // 4624 floats
  __shared__ float a_sB[4 * APITCH];   // 4624 floats
  __shared__ float red2[64 * RPITCH];  // 16896 floats (time-shared A/B)
  __shared__ float c2_s[32], u0_s[32];
  const int tid = threadIdx.x;
  const int bid = blockIdx.x;
  const int cg = ((bid & 7) << 2) | ((bid >> 3) & 3);
  const int rg = bid >> 5;
  const int w = tid >> 6, l = tid & 63;
  const int ci = l & 7;
  const int sp = w * 8 + (l >> 3);  // K-slice in [0,64)
  const int cb = 4 * ci, k0 = 16 * sp;
  const int abase_k = 36 * (sp >> 1) + 16 * (sp & 1);
  // finalize coords: u-lanes tid<128, y-lanes tid 128..255; same (row,fu) map
  const int ro = (tid & 127) >> 5;  // row within group [0,4)
  const int fu = 32 * cg + (tid & 31);
  const int rowA = 4 * rg + ro;       // global rows 0..31
  const int rowB = 32 + rowA;         // global rows 32..63
  // staging coords: rows {tb, tb+2}, cg-rotated k
  const int tb = tid >> 8;                      // 0 or 1
  const int kq = ((tid & 255) + 8 * cg) & 255;  // f4-unit index
  const int lofs = 36 * (kq >> 3) + ((4 * kq) & 31);
  unsigned* const flagsA = flags;
  unsigned* const flagsB = flags + 256;

  // ===== PROLOGUE (R12-proven): w2reg = frag of W2 = w_out@w_y; c2; u0 =====
  float* const wos = red2;   // [1024][WOPITCH] aliases red2
  float* const wys = a_sA;   // [8][36] aliases a_sA
  f4 w2reg[16];
#pragma unroll
  for (int jj = 0; jj < 16; ++jj) w2reg[jj] = (f4){0.f, 0.f, 0.f, 0.f};
  f4 c2a = (f4){0.f, 0.f, 0.f, 0.f}, u0a = (f4){0.f, 0.f, 0.f, 0.f};
  {
    f4 nx0, nx1, nx2, nx3, nwy;
    {
      const float* wo = w_out + (size_t)tid * U;
      nx0 = *(const f4*)wo;
      nx1 = *(const f4*)(wo + 4);
      const float* wo2 = w_out + (size_t)(tid + 512) * U;
      nx2 = *(const f4*)wo2;
      nx3 = *(const f4*)(wo2 + 4);
      if (tid < 64)
        nwy = *(const f4*)(w_y + (size_t)(tid >> 3) * U + 32 * cg +
                           4 * (tid & 7));
    }
    for (int mi = 0; mi < 128; ++mi) {
      const int m0 = mi * 8;
#pragma unroll
      for (int q = 0; q < 4; ++q) {
        wos[tid * WOPITCH + q] = nx0[q];
        wos[tid * WOPITCH + 4 + q] = nx1[q];
        wos[(tid + 512) * WOPITCH + q] = nx2[q];
        wos[(tid + 512) * WOPITCH + 4 + q] = nx3[q];
      }
      if (tid < 64) *(f4*)&wys[(tid >> 3) * 36 + 4 * (tid & 7)] = nwy;
      __syncthreads();
      if (mi < 127) {
        const int m1 = m0 + 8;
        const float* wo = w_out + (size_t)tid * U + m1;
        nx0 = *(const f4*)wo;
        nx1 = *(const f4*)(wo + 4);
        const float* wo2 = w_out + (size_t)(tid + 512) * U + m1;
        nx2 = *(const f4*)wo2;
        nx3 = *(const f4*)(wo2 + 4);
        if (tid < 64)
          nwy = *(const f4*)(w_y + (size_t)(m1 + (tid >> 3)) * U + 32 * cg +
                             4 * (tid & 7));
      }
#pragma unroll
      for (int mm = 0; mm < 8; ++mm) {
        const f4 wy = *(const f4*)&wys[mm * 36 + cb];
#pragma unroll
        for (int jj = 0; jj < 16; ++jj)
          w2reg[jj] += wos[(16 * sp + jj) * WOPITCH + mm] * wy;
        if (tid < 8) {
          c2a += b_out[m0 + mm] * wy;
          u0a += h0[m0 + mm] * wy;
        }
      }
      __syncthreads();
    }
  }
  if (tid < 8) {
    *(f4*)&c2_s[cb] = c2a;
    *(f4*)&u0_s[cb] = u0a;
  }
  __syncthreads();

  // ===== bootstrap: state regs; h1(t=0) both chains -> slot0; post 1,1 =====
  float uA = 0.f, uB = 0.f, yA = 0.f, yB = 0.f, c2_lane = 0.f;
  if (tid < 128) {
    c2_lane = c2_s[tid & 31];
    uA = u0_s[tid & 31];
    uB = uA;
    float h1A = LRELU(uA + xp[(size_t)rowA * U + fu]);  // t=0
    float h1B = LRELU(uB + xp[(size_t)rowB * U + fu]);
    llc_store(slots + (size_t)rowA * U + fu, h1A);  // slot0
    llc_store(slots + (size_t)rowB * U + fu, h1B);
  } else if (tid < 256) {
    yA = h0[fu];
    yB = yA;
  }
  asm volatile("" ::: "memory");
  __builtin_amdgcn_s_waitcnt(0);
  __syncthreads();
  if (tid == 0) {
    llc_post(&flagsA[rg * 32 + cg], 1u);
    llc_post(&flagsB[rg * 32 + cg], 1u);
  }
  // pre-stage a_sA for phase 1 (slot parity 0, chain-A rows)
  {
    if (tid < 64) {
      const unsigned* fp = &flagsA[rg * 32 + (l & 31)];
      while (!__all(llc_flag(fp) >= 1u)) __builtin_amdgcn_s_sleep(1);
    }
    __syncthreads();
    asm volatile("" ::: "memory");
    const float* pb = slots + (size_t)(4 * rg) * U + 4 * kq;
    f4 av0, av1;
    asm volatile("global_load_dwordx4 %0, %1, off sc1"
                 : "=v"(av0) : "v"(pb + (size_t)tb * U));
    asm volatile("global_load_dwordx4 %0, %1, off sc1"
                 : "=v"(av1) : "v"(pb + (size_t)(tb + 2) * U));
    asm volatile("s_waitcnt vmcnt(0)" ::: "memory");
    *(f4*)&a_sA[(tb + 0) * APITCH + lofs] = av0;
    *(f4*)&a_sA[(tb + 2) * APITCH + lofs] = av1;
  }
  // wreg = Wh0 for S=1
  f4 wreg[16];
  {
    const float* wp = w_h + (size_t)k0 * U + 32 * cg + cb;
#pragma unroll
    for (int jj = 0; jj < 16; ++jj) wreg[jj] = *(const f4*)(wp + (size_t)jj * U);
  }

  // ===== MAIN LOOP: 768 superphases, each = phase S of chain A AND B =====
  for (int S = 1; S <= 3 * T; ++S) {
    const int j = (S - 1) % 3, t = (S - 1) / 3;
    float* const slotw = slots + (size_t)(S & 1) * BU;
    // -- 1. poll flagB >= S; barrier (also orders prev-tail a_sA writes) --
    if (tid < 64) {
      const unsigned tgt = (unsigned)S;
      const unsigned* fp = &flagsB[rg * 32 + (l & 31)];
      while (!__all(llc_flag(fp) >= tgt)) __builtin_amdgcn_s_sleep(1);
    }
    __syncthreads();
    asm volatile("" ::: "memory");
    // -- 2. issue B stage loads (phase S input, chain-B rows) --
    f4 bv0, bv1;
    {
      const float* pb =
          slots + (size_t)((S + 1) & 1) * BU + (size_t)(32 + 4 * rg) * U + 4 * kq;
      asm volatile("global_load_dwordx4 %0, %1, off sc1"
                   : "=v"(bv0) : "v"(pb + (size_t)tb * U));
      asm volatile("global_load_dwordx4 %0, %1, off sc1"
                   : "=v"(bv1) : "v"(pb + (size_t)(tb + 2) * U));
    }
    // -- 2b. finalize-operand prefetch --
    float preU = 0.f, preXA = 0.f, preXB = 0.f, preY = 0.f;
    if (tid < 128) {
      if (j < 2)
        preU = b_h[j * U + fu];
      else if (t < T - 1) {
        preXA = xp[((size_t)(t + 1) * B + rowA) * U + fu];
        preXB = xp[((size_t)(t + 1) * B + rowB) * U + fu];
      }
    } else if (tid < 256 && j == 2)
      preY = b_out[fu];
    // -- 3. A-compute (covers B-load latency) --
    f4 acc[4], accY[4];
#pragma unroll
    for (int r = 0; r < 4; ++r) acc[r] = accY[r] = (f4){0.f, 0.f, 0.f, 0.f};
    if (j == 2)
      TILE4D(acc, accY, w2reg, wreg, a_sA);
    else
      TILE4(acc, wreg, a_sA);
    // -- 4. write red2: u-partials [0..128), y-partials [128..256) --
#pragma unroll
    for (int r = 0; r < 4; ++r)
      *(f4*)&red2[sp * RPITCH + r * 32 + cb] = acc[r];
    if (j == 2) {
#pragma unroll
      for (int r = 0; r < 4; ++r)
        *(f4*)&red2[sp * RPITCH + 128 + r * 32 + cb] = accY[r];
    }
    __syncthreads();
    // -- 5. finalize A --
    if (tid < 128) {
      RED64(sum);
      float* dst = slotw + (size_t)rowA * U + fu;
      if (j < 2) {
        llc_store(dst, LRELU(sum + preU));
      } else {
        uA += sum + c2_lane;
        llc_store(dst, LRELU(uA + preXA));
      }
    } else if (tid < 256 && j == 2) {
      RED64(sum);
      yA += sum + preY;
    }
    // -- 6. drain (A stores + B loads) + post flagA = S+1 --
    asm volatile("" ::: "memory");
    __builtin_amdgcn_s_waitcnt(0);
    __syncthreads();
    if (tid == 0) llc_post(&flagsA[rg * 32 + cg], (unsigned)(S + 1));
    // -- 7. out-store A (off-chain) --
    if (j == 2 && tid >= 128 && tid < 256)
      out[((size_t)rowA * T + t) * U + fu] = yA;
    // -- 8. write staged B -> a_sB --
    *(f4*)&a_sB[(tb + 0) * APITCH + lofs] = bv0;
    *(f4*)&a_sB[(tb + 2) * APITCH + lofs] = bv1;
    // -- 9. poll flagA >= S+1; barrier (orders a_sB writes vs reads) --
    if (tid < 64) {
      const unsigned tgt = (unsigned)(S + 1);
      const unsigned* fp = &flagsA[rg * 32 + (l & 31)];
      while (!__all(llc_flag(fp) >= tgt)) __builtin_amdgcn_s_sleep(1);
    }
    __syncthreads();
    asm volatile("" ::: "memory");
    // -- 10. issue A stage loads for phase S+1 (slot parity S&1) --
    f4 av0, av1;
    if (S < 3 * T) {
      const float* pb =
          slots + (size_t)(S & 1) * BU + (size_t)(4 * rg) * U + 4 * kq;
      asm volatile("global_load_dwordx4 %0, %1, off sc1"
                   : "=v"(av0) : "v"(pb + (size_t)tb * U));
      asm volatile("global_load_dwordx4 %0, %1, off sc1"
                   : "=v"(av1) : "v"(pb + (size_t)(tb + 2) * U));
    }
    // -- 11. B-compute (covers A-load latency) --
#pragma unroll
    for (int r = 0; r < 4; ++r) acc[r] = accY[r] = (f4){0.f, 0.f, 0.f, 0.f};
    if (j == 2)
      TILE4D(acc, accY, w2reg, wreg, a_sB);
    else
      TILE4(acc, wreg, a_sB);
    // -- 12. write red2; barrier --
#pragma unroll
    for (int r = 0; r < 4; ++r)
      *(f4*)&red2[sp * RPITCH + r * 32 + cb] = acc[r];
    if (j == 2) {
#pragma unroll
      for (int r = 0; r < 4; ++r)
        *(f4*)&red2[sp * RPITCH + 128 + r * 32 + cb] = accY[r];
    }
    __syncthreads();
    // -- 13. finalize B --
    if (tid < 128) {
      RED64(sum);
      float* dst = slotw + (size_t)rowB * U + fu;
      if (j < 2) {
        llc_store(dst, LRELU(sum + preU));
      } else {
        uB += sum + c2_lane;
        llc_store(dst, LRELU(uB + preXB));
      }
    } else if (tid < 256 && j == 2) {
      RED64(sum);
      yB += sum + preY;
    }
    // -- 14. drain (B stores + A loads) + post flagB = S+1 --
    asm volatile("" ::: "memory");
    __builtin_amdgcn_s_waitcnt(0);
    __syncthreads();
    if (tid == 0) llc_post(&flagsB[rg * 32 + cg], (unsigned)(S + 1));
    // -- 15. out-store B (off-chain) --
    if (j == 2 && tid >= 128 && tid < 256)
      out[((size_t)rowB * T + t) * U + fu] = yB;
    // -- 16. write staged A -> a_sA (read next superphase after top barrier) --
    if (S < 3 * T) {
      *(f4*)&a_sA[(tb + 0) * APITCH + lofs] = av0;
      *(f4*)&a_sA[(tb + 2) * APITCH + lofs] = av1;
    }
    // -- 17. W prefetch for next superphase: j0->Wh1, j1->w_out, j2->Wh0 --
    if (S < 3 * T) {
      const float* Wn = (j == 0) ? (w_h + (size_t)U * U)
                        : (j == 1) ? w_out
                                   : w_h;
      const float* wp = Wn + (size_t)k0 * U + 32 * cg + cb;
#pragma unroll
      for (int jj = 0; jj < 16; ++jj)
        wreg[jj] = *(const f4*)(wp + (size_t)jj * U);
    }
  }
}

extern "C" void kernel_launch(void* const* d_in, const int* in_sizes, int n_in,
                              void* d_out, int out_size, void* d_ws,
                              size_t ws_size, hipStream_t stream) {
  const int* x = (const int*)d_in[0];
  const float* emb = (const float*)d_in[1];
  const float* w_y = (const float*)d_in[2];
  const float* w_x = (const float*)d_in[3];
  const float* b_in = (const float*)d_in[4];
  const float* w_h = (const float*)d_in[5];
  const float* b_h = (const float*)d_in[6];
  const float* w_out = (const float*)d_in[7];
  const float* b_out = (const float*)d_in[8];
  const float* h0 = (const float*)d_in[9];
  float* out = (float*)d_out;

  // workspace (floats): xproj | slots[2] | (dead) | flags — layout
  // IDENTICAL to R11/R12; footprint unchanged (R10 lesson).
  float* ws = (float*)d_ws;
  float* xpb = ws;                         // T*B*U
  float* slots = xpb + (size_t)T * B * U;  // 2*BU
  float* dead = slots + 2 * (size_t)BU;    // BU (unused)
  unsigned* flags = (unsigned*)(dead + (size_t)BU);  // 512 uints (A|B)

  k_init<<<2, 256, 0, stream>>>(flags);
  dim3 g1(256, 16);
  k_xproj<<<g1, 256, 0, stream>>>(x, emb, w_x, b_in, xpb);

  void* args[] = {&xpb,   &w_y, &w_h, &b_h,   &w_out,
                  &b_out, &h0,  &out, &slots, &flags};
  hipLaunchCooperativeKernel((void*)k_seq, dim3(256), dim3(512), args, 0u,
                             stream);
}

// Round 8
// 5237.456 us; speedup vs baseline: 1.2309x; 1.2309x over previous
//
#include <hip/hip_runtime.h>

// HighwayLayerDiscrete: 256-step recurrent highway net, batch 64, units 1024.
// Step t: h1=lrelu(y@w_y+xp[t]); h2=lrelu(h1@Wh0+b0); h3=lrelu(h2@Wh1+b1);
// y += h3@w_out + b_out; out[:,t,:]=y.   u-recurrence (R12): u += h3@W2 + c2,
// h1' = lrelu(u + xp[t+1]), W2 = w_out@w_y (per-thread frags in w2reg).
//
// R15 = R12 (4.83 ms, PASSED) + INCREMENTAL PER-PRODUCER STAGING.
// R14 post-mortem (2nd XCD-local failure): if HW_REG_XCC_ID misreads, the
// ticket wraps -> duplicate (rg,cg) + empty groups -> poll deadlock; sc0
// polling in the wrong L2 never converges. XCD-local exchange ABANDONED.
// This round keeps the R12 structure + proven sc1 device-scope protocol
// and removes the poll->stage serialization: producer cg' owns cols
// [32cg',32cg'+32) of the consumer's 8 rows = 64 f4 = 1 f4/lane/wave.
// Each of the 8 waves handles 4 producer slabs (rotation by cg spreads
// LLC lines): poll that producer's flag -> issue slab loads immediately;
// one vmcnt(0) + 4 LDS writes + single __syncthreads. Staging of ready
// slabs overlaps the straggler wait; the global poll barrier is gone.
// Same acquire semantics per slab (flag>=Q observed before dependent data
// loads issue); producers/posts unchanged -> no new hang mode.
// Carried invariants: 256 coop blocks x 512 thr (R4); no cross-WG split-K
// (R2/R3); no cache fences (R1); sc1 device-scope exchange only (R10/R14);
// release = waitcnt0+barrier+flag; per-producer flags, 512-uint footprint
// (R8/R10); finalize-operand prefetch (R8); K-retile 64x16, unique W
// frags, de-aliased red2 (R9); LDS skew injective (R5); W2 prologue +
// 3-phase + off-chain y (R12). Arithmetic identical to R12 -> absmax must
// equal 1.584563e+29.

constexpr int B = 64, T = 256, U = 1024, E = 512;
constexpr int BU = B * U;     // 65536
constexpr int APITCH = 1156;  // A-row pitch (1024 + 36-skew; ==4 mod 8)
constexpr int RPITCH = 264;   // red2 slice pitch (256 + 8)
constexpr int WOPITCH = 9;    // prologue w_out_s pitch

#define LRELU(v) ((v) > 0.f ? (v) : 0.2f * (v))

using f4 = float __attribute__((ext_vector_type(4)));

__device__ __forceinline__ void llc_store(float* p, float v) {
  __hip_atomic_store(p, v, __ATOMIC_RELAXED, __HIP_MEMORY_SCOPE_AGENT);
}
__device__ __forceinline__ unsigned llc_flag(const unsigned* p) {
  return __hip_atomic_load(p, __ATOMIC_RELAXED, __HIP_MEMORY_SCOPE_AGENT);
}
__device__ __forceinline__ void llc_post(unsigned* p, unsigned v) {
  __hip_atomic_store(p, v, __ATOMIC_RELAXED, __HIP_MEMORY_SCOPE_AGENT);
}

// 8x4x(K=16) tile from LDS a_s x register bank WB -> acc[8]
#define COMPUTE_ACC(WB)                                          \
  do {                                                           \
    _Pragma("unroll") for (int r = 0; r < 8; ++r) acc[r] =       \
        (f4){0.f, 0.f, 0.f, 0.f};                                \
    _Pragma("unroll") for (int q = 0; q < 4; ++q) {              \
      const f4 w0 = WB[4 * q], w1 = WB[4 * q + 1];               \
      const f4 w2 = WB[4 * q + 2], w3 = WB[4 * q + 3];           \
      const int ab = abase_k + 4 * q;                            \
      _Pragma("unroll") for (int r = 0; r < 8; ++r) {            \
        f4 a = *(const f4*)&a_s[r * APITCH + ab];                \
        acc[r] += a.x * w0 + a.y * w1 + a.z * w2 + a.w * w3;     \
      }                                                          \
    }                                                            \
  } while (0)

// ---------------- init: zero flags ----------------
__global__ void k_init(unsigned* __restrict__ flags) {
  int tid = blockIdx.x * 256 + threadIdx.x;
  if (tid < 512) flags[tid] = 0u;
}

// ------- xproj[t*64+n][u] = emb[x[n][t]] @ w_x + b_in (R2/R3-proven) -------
__global__ __launch_bounds__(256) void k_xproj(
    const int* __restrict__ x, const float* __restrict__ emb,
    const float* __restrict__ w_x, const float* __restrict__ b_in,
    float* __restrict__ xp) {
  __shared__ float a_s[64][36];
  __shared__ float w_s[32][64];
  __shared__ int idxs[64];
  const int tid = threadIdx.x;
  const int m0 = blockIdx.x * 64;
  const int c0 = blockIdx.y * 64;
  if (tid < 64) {
    int m = m0 + tid;
    idxs[tid] = x[(m & 63) * T + (m >> 6)];  // x[n][t], row m = t*64+n
  }
  __syncthreads();
  const int rq = tid >> 4, cq = tid & 15;
  float acc[4][4] = {};
  for (int k0 = 0; k0 < E; k0 += 32) {
#pragma unroll
    for (int rep = 0; rep < 8; ++rep) {
      int e = rep * 256 + tid;
      int r = e >> 5, k = e & 31;
      a_s[r][k] = emb[(size_t)idxs[r] * E + k0 + k];
    }
#pragma unroll
    for (int rep = 0; rep < 2; ++rep) {
      int e = rep * 256 + tid;
      int kr = e >> 4, q = e & 15;
      *(float4*)&w_s[kr][4 * q] =
          *(const float4*)(w_x + (size_t)(k0 + kr) * U + c0 + 4 * q);
    }
    __syncthreads();
#pragma unroll
    for (int kc = 0; kc < 32; kc += 4) {
      float4 a4[4], w4[4];
#pragma unroll
      for (int i = 0; i < 4; ++i) a4[i] = *(const float4*)&a_s[4 * rq + i][kc];
#pragma unroll
      for (int kk = 0; kk < 4; ++kk)
        w4[kk] = *(const float4*)&w_s[kc + kk][4 * cq];
#pragma unroll
      for (int i = 0; i < 4; ++i) {
        const float av[4] = {a4[i].x, a4[i].y, a4[i].z, a4[i].w};
#pragma unroll
        for (int kk = 0; kk < 4; ++kk) {
          acc[i][0] += av[kk] * w4[kk].x;
          acc[i][1] += av[kk] * w4[kk].y;
          acc[i][2] += av[kk] * w4[kk].z;
          acc[i][3] += av[kk] * w4[kk].w;
        }
      }
    }
    __syncthreads();
  }
  const float4 bb = *(const float4*)(b_in + c0 + 4 * cq);
  const float bv[4] = {bb.x, bb.y, bb.z, bb.w};
#pragma unroll
  for (int i = 0; i < 4; ++i) {
    float4 o;
    o.x = acc[i][0] + bv[0];
    o.y = acc[i][1] + bv[1];
    o.z = acc[i][2] + bv[2];
    o.w = acc[i][3] + bv[3];
    *(float4*)(xp + (size_t)(m0 + 4 * rq + i) * U + c0 + 4 * cq) = o;
  }
}

// ---------------- sequential pipeline ----------------
// 256 WGs. cg = (bid&7)*4 + ((bid>>3)&3), rg = bid>>5 (R11 mapping, W
// L2-resident under default round-robin). Thread (s',ci): K-slice
// [16s',16s'+16), ALL 8 rows, cols [4ci,4ci+4) of 32.
__global__ __launch_bounds__(512, 2) void k_seq(
    const float* __restrict__ xp, const float* __restrict__ w_y,
    const float* __restrict__ w_h, const float* __restrict__ b_h,
    const float* __restrict__ w_out, const float* __restrict__ b_out,
    const float* __restrict__ h0, float* __restrict__ out,
    float* __restrict__ slots, unsigned* __restrict__ flags) {
  __shared__ float a_s[8 * APITCH];    // 9248 floats
  __shared__ float red2[64 * RPITCH];  // 16896 floats
  __shared__ float c2_s[32], u0_s[32];
  const int tid = threadIdx.x;
  const int bid = blockIdx.x;
  const int cg = ((bid & 7) << 2) | ((bid >> 3) & 3);  // XCD-affine W slab
  const int rg = bid >> 5;
  const int w = tid >> 6, l = tid & 63;
  const int ci = l & 7;
  const int sp = w * 8 + (l >> 3);  // K-slice in [0,64)
  const int cb = 4 * ci, k0 = 16 * sp;
  const int abase_k = 36 * (sp >> 1) + 16 * (sp & 1);
  // finalize-lane coords (valid for tid < 256)
  const int frow = 8 * rg + (tid >> 5);
  const int fu = 32 * cg + (tid & 31);
  // incremental-staging lane coords: row = l>>3, f4-col within slab = l&7
  const int srow = l >> 3, scol = l & 7;

  // ===== PROLOGUE (R12-proven): w2reg = frag of W2 = w_out@w_y; c2; u0 =====
  float* const wos = red2;  // [1024][WOPITCH] aliases red2
  float* const wys = a_s;   // [8][36] aliases a_s
  f4 w2reg[16];
#pragma unroll
  for (int jj = 0; jj < 16; ++jj) w2reg[jj] = (f4){0.f, 0.f, 0.f, 0.f};
  f4 c2a = (f4){0.f, 0.f, 0.f, 0.f}, u0a = (f4){0.f, 0.f, 0.f, 0.f};
  {
    f4 nx0, nx1, nx2, nx3, nwy;
    {
      const float* wo = w_out + (size_t)tid * U;
      nx0 = *(const f4*)wo;
      nx1 = *(const f4*)(wo + 4);
      const float* wo2 = w_out + (size_t)(tid + 512) * U;
      nx2 = *(const f4*)wo2;
      nx3 = *(const f4*)(wo2 + 4);
      if (tid < 64)
        nwy = *(const f4*)(w_y + (size_t)(tid >> 3) * U + 32 * cg +
                           4 * (tid & 7));
    }
    for (int mi = 0; mi < 128; ++mi) {
      const int m0 = mi * 8;
#pragma unroll
      for (int q = 0; q < 4; ++q) {
        wos[tid * WOPITCH + q] = nx0[q];
        wos[tid * WOPITCH + 4 + q] = nx1[q];
        wos[(tid + 512) * WOPITCH + q] = nx2[q];
        wos[(tid + 512) * WOPITCH + 4 + q] = nx3[q];
      }
      if (tid < 64) *(f4*)&wys[(tid >> 3) * 36 + 4 * (tid & 7)] = nwy;
      __syncthreads();
      if (mi < 127) {
        const int m1 = m0 + 8;
        const float* wo = w_out + (size_t)tid * U + m1;
        nx0 = *(const f4*)wo;
        nx1 = *(const f4*)(wo + 4);
        const float* wo2 = w_out + (size_t)(tid + 512) * U + m1;
        nx2 = *(const f4*)wo2;
        nx3 = *(const f4*)(wo2 + 4);
        if (tid < 64)
          nwy = *(const f4*)(w_y + (size_t)(m1 + (tid >> 3)) * U + 32 * cg +
                             4 * (tid & 7));
      }
#pragma unroll
      for (int mm = 0; mm < 8; ++mm) {
        const f4 wy = *(const f4*)&wys[mm * 36 + cb];
#pragma unroll
        for (int jj = 0; jj < 16; ++jj)
          w2reg[jj] += wos[(16 * sp + jj) * WOPITCH + mm] * wy;
        if (tid < 8) {
          c2a += b_out[m0 + mm] * wy;
          u0a += h0[m0 + mm] * wy;
        }
      }
      __syncthreads();
    }
  }
  if (tid < 8) {
    *(f4*)&c2_s[cb] = c2a;
    *(f4*)&u0_s[cb] = u0a;
  }
  __syncthreads();
  // bootstrap: u,y registers; h1_0 -> slot0; release (post=1)
  float u_reg = 0.f, y_reg = 0.f, c2_lane = 0.f;
  if (tid < 256) {
    c2_lane = c2_s[tid & 31];
    u_reg = u0_s[tid & 31];
    y_reg = h0[fu];
    float h1 = LRELU(u_reg + xp[(size_t)frow * U + fu]);  // t=0
    llc_store(slots + (size_t)frow * U + fu, h1);         // slot0
  }
  asm volatile("" ::: "memory");
  __builtin_amdgcn_s_waitcnt(0);
  __syncthreads();
  if (tid == 0) llc_post(&flags[rg * 32 + cg], 1u);

  // W prefetch for Q=1 (Wh0)
  f4 wreg[16];
  {
    const float* wp = w_h + (size_t)k0 * U + 32 * cg + cb;
#pragma unroll
    for (int jj = 0; jj < 16; ++jj)
      wreg[jj] = *(const f4*)(wp + (size_t)jj * U);
  }

  // ============ MAIN LOOP: 3 phases per step ============
  for (int Q = 1; Q <= 3 * T; ++Q) {
    const int j = (Q - 1) % 3, t = (Q - 1) / 3;
    const float* Asrc =
        slots + (size_t)((Q + 1) & 1) * BU + (size_t)(8 * rg) * U;
    float* slotw = slots + (size_t)(Q & 1) * BU;
    // ---- 1. finalize-operand prefetch (independent of phase data) ----
    float preA = 0.f, preB = 0.f;
    if (tid < 256) {
      if (j == 0)
        preA = b_h[fu];
      else if (j == 1)
        preA = b_h[U + fu];
      else {
        if (t < T - 1) preA = xp[((size_t)(t + 1) * B + frow) * U + fu];
        preB = b_out[fu];
      }
    }
    // ---- 2. INCREMENTAL stage: wave w polls its 4 producer slabs and
    //         issues each slab's loads the moment that flag lands.
    //         slab(pc) = cols [32pc,32pc+32) of 8 rows = 1 f4/lane. ----
    {
      f4 sv0, sv1, sv2, sv3;
      int sd0, sd1, sd2, sd3;
#define STAGE_SLAB(I, SV, SD)                                              \
      {                                                                    \
        const int pc = ((w << 2) + I + cg) & 31;                           \
        const unsigned* fp = &flags[rg * 32 + pc];                         \
        while (!__all(llc_flag(fp) >= (unsigned)Q))                        \
          __builtin_amdgcn_s_sleep(1);                                     \
        asm volatile("" ::: "memory");                                     \
        const float* pb =                                                  \
            Asrc + (size_t)srow * U + (size_t)(32 * pc + 4 * scol);        \
        asm volatile("global_load_dwordx4 %0, %1, off sc1"                 \
                     : "=v"(SV)                                            \
                     : "v"(pb));                                           \
        SD = srow * APITCH + 36 * pc + 4 * scol;                           \
      }
      STAGE_SLAB(0, sv0, sd0)
      STAGE_SLAB(1, sv1, sd1)
      STAGE_SLAB(2, sv2, sd2)
      STAGE_SLAB(3, sv3, sd3)
#undef STAGE_SLAB
      asm volatile("s_waitcnt vmcnt(0)" ::: "memory");
      *(f4*)&a_s[sd0] = sv0;
      *(f4*)&a_s[sd1] = sv1;
      *(f4*)&a_s[sd2] = sv2;
      *(f4*)&a_s[sd3] = sv3;
    }
    __syncthreads();
    // ---- 3. on-chain matmul: Wh0/Wh1 from wreg, W2 from persistent regs ----
    f4 acc[8];
    if (j == 2)
      COMPUTE_ACC(w2reg);
    else
      COMPUTE_ACC(wreg);
#pragma unroll
    for (int r = 0; r < 8; ++r)
      *(f4*)&red2[sp * RPITCH + r * 32 + cb] = acc[r];
    __syncthreads();
    // ---- 4. finalize: sum 64 partials, update state, store exchange ----
    if (tid < 256) {
      float s0 = 0.f, s1 = 0.f, s2 = 0.f, s3 = 0.f;
#pragma unroll
      for (int z = 0; z < 64; z += 4) {
        s0 += red2[(z + 0) * RPITCH + tid];
        s1 += red2[(z + 1) * RPITCH + tid];
        s2 += red2[(z + 2) * RPITCH + tid];
        s3 += red2[(z + 3) * RPITCH + tid];
      }
      const float sum = (s0 + s1) + (s2 + s3);
      const size_t yi = (size_t)frow * U + fu;
      if (j < 2) {
        llc_store(slotw + yi, LRELU(sum + preA));  // h2 / h3
      } else {
        u_reg += sum + c2_lane;                      // u_{t+1}
        llc_store(slotw + yi, LRELU(u_reg + preA));  // h1_{t+1}
      }
    }
    // ---- 5. drain + release ----
    asm volatile("" ::: "memory");
    __builtin_amdgcn_s_waitcnt(0);
    __syncthreads();
    if (tid == 0) llc_post(&flags[rg * 32 + cg], (unsigned)(Q + 1));
    // ---- 6. j==2 OFF-CHAIN: y += h3@w_out + b_out; out[:,t,:] = y ----
    if (j == 2) {
      f4 acc2[8];
      {
        f4* acc = acc2;               // reuse macro
        if (true) COMPUTE_ACC(wreg);  // wreg holds w_out here
      }
#pragma unroll
      for (int r = 0; r < 8; ++r)
        *(f4*)&red2[sp * RPITCH + r * 32 + cb] = acc2[r];
      __syncthreads();
      if (tid < 256) {
        float s0 = 0.f, s1 = 0.f, s2 = 0.f, s3 = 0.f;
#pragma unroll
        for (int z = 0; z < 64; z += 4) {
          s0 += red2[(z + 0) * RPITCH + tid];
          s1 += red2[(z + 1) * RPITCH + tid];
          s2 += red2[(z + 2) * RPITCH + tid];
          s3 += red2[(z + 3) * RPITCH + tid];
        }
        y_reg += (s0 + s1) + (s2 + s3) + preB;
        out[((size_t)frow * T + t) * U + fu] = y_reg;
      }
    }
    // ---- 7. W prefetch for next phase: j0->Wh1, j1->w_out, j2->Wh0 ----
    if (Q < 3 * T) {
      const float* Wn = (j == 0)   ? (w_h + (size_t)U * U)
                        : (j == 1) ? w_out
                                   : w_h;
      const float* wp = Wn + (size_t)k0 * U + 32 * cg + cb;
#pragma unroll
      for (int jj = 0; jj < 16; ++jj)
        wreg[jj] = *(const f4*)(wp + (size_t)jj * U);
    }
  }
}

extern "C" void kernel_launch(void* const* d_in, const int* in_sizes, int n_in,
                              void* d_out, int out_size, void* d_ws,
                              size_t ws_size, hipStream_t stream) {
  const int* x = (const int*)d_in[0];
  const float* emb = (const float*)d_in[1];
  const float* w_y = (const float*)d_in[2];
  const float* w_x = (const float*)d_in[3];
  const float* b_in = (const float*)d_in[4];
  const float* w_h = (const float*)d_in[5];
  const float* b_h = (const float*)d_in[6];
  const float* w_out = (const float*)d_in[7];
  const float* b_out = (const float*)d_in[8];
  const float* h0 = (const float*)d_in[9];
  float* out = (float*)d_out;

  // workspace (floats): xproj | slots[2] | (dead) | flags — layout
  // IDENTICAL to R11/R12; footprint unchanged (R10 lesson).
  float* ws = (float*)d_ws;
  float* xpb = ws;                         // T*B*U
  float* slots = xpb + (size_t)T * B * U;  // 2*BU
  float* dead = slots + 2 * (size_t)BU;    // BU (unused)
  unsigned* flags = (unsigned*)(dead + (size_t)BU);  // 512 uints

  k_init<<<2, 256, 0, stream>>>(flags);
  dim3 g1(256, 16);
  k_xproj<<<g1, 256, 0, stream>>>(x, emb, w_x, b_in, xpb);

  void* args[] = {&xpb,   &w_y, &w_h, &b_h,   &w_out,
                  &b_out, &h0,  &out, &slots, &flags};
  hipLaunchCooperativeKernel((void*)k_seq, dim3(256), dim3(512), args, 0u,
                             stream);
}